// Round 3
// baseline (2551.053 us; speedup 1.0000x reference)
//
#include <hip/hip_runtime.h>
#include <math.h>

#define B_    16
#define QL_   32
#define DL_   12
#define RSZ_  500
#define T_    2
#define DW_   256
#define DH_   512
#define HP_   256
#define NW_   50000
#define NE_   100000
#define NSEQD (T_*B_*RSZ_)   // 16000
#define MDESC 128            // seqs per desc block
#define NBLK_DESC 250        // 125 per dir
#define NBLK_FUSED 252       // + 2 q-gru blocks

typedef _Float16 half8 __attribute__((ext_vector_type(8)));
typedef float   floatx4 __attribute__((ext_vector_type(4)));

__device__ __forceinline__ float sigf(float x){
  return __builtin_amdgcn_rcpf(1.0f + __expf(-x));
}
__device__ __forceinline__ float tanhfast(float x){
  return 1.0f - 2.0f*__builtin_amdgcn_rcpf(1.0f + __expf(2.0f*x));
}

// ---------------------------------------------------------------------------
// Desc-GRU fp16 B^T weights. Per dir (393216 elems):
//   [0, 262144):        Brz [n=512][k=512]  n<256: r_n, n>=256: z_{n-256};
//                       k<256 from Wx row n, k>=256 from Wh row n.
//   [262144, 327680):   Bxn [j=256][k=256]  = Wx row 512+j
//   [327680, 393216):   Bgn [j=256][k=256]  = Wh row 512+j
// ---------------------------------------------------------------------------
__global__ void k_prep_desc(const float* __restrict__ Wx, const float* __restrict__ Wh,
                            _Float16* __restrict__ Bd) {
  int i = blockIdx.x*256 + threadIdx.x;     // 786432 total
  int dir = i / 393216;
  int rem = i % 393216;
  float v;
  if (rem < 262144) {
    int n = rem >> 9, k = rem & 511;
    v = (k < 256) ? Wx[(dir*768 + n)*256 + k] : Wh[(dir*768 + n)*256 + (k-256)];
  } else if (rem < 327680) {
    int r2 = rem - 262144; int j = r2 >> 8, k = r2 & 255;
    v = Wx[(dir*768 + 512 + j)*256 + k];
  } else {
    int r2 = rem - 327680; int j = r2 >> 8, k = r2 & 255;
    v = Wh[(dir*768 + 512 + j)*256 + k];
  }
  Bd[i] = (_Float16)v;
}

// q-GRU recurrent weight fp32 -> fp16, same [dir][768][256] layout
__global__ void k_prep_qwh(const float* __restrict__ Wh, _Float16* __restrict__ WhQ) {
  int i = blockIdx.x*256 + threadIdx.x;     // 393216
  WhQ[i] = (_Float16)Wh[i];
}

// embedding fp32 -> fp16 (identical rounding to the in-kernel stage cvt)
__global__ void k_prep_emb16(const float* __restrict__ emb, _Float16* __restrict__ emb16) {
  int i = blockIdx.x*256 + threadIdx.x;     // 1.6M threads, 8 floats each
  const float4* s = (const float4*)emb + (size_t)i*2;
  float4 a = s[0], b = s[1];
  half8 h;
  h[0]=(_Float16)a.x; h[1]=(_Float16)a.y; h[2]=(_Float16)a.z; h[3]=(_Float16)a.w;
  h[4]=(_Float16)b.x; h[5]=(_Float16)b.y; h[6]=(_Float16)b.z; h[7]=(_Float16)b.w;
  *(half8*)(emb16 + (size_t)i*8) = h;
}

// ---------------------------------------------------------------------------
// Q-GRU x-projection (unchanged): xp[dir][l][b][768].
// ---------------------------------------------------------------------------
__global__ __launch_bounds__(256) void k_xproj(
    const int* __restrict__ questions, const float* __restrict__ emb,
    const float* __restrict__ Wx, const float* __restrict__ bx,
    float* __restrict__ xp)
{
  int b = blockIdx.x, n0 = blockIdx.y*128, dir = blockIdx.z;
  int tid = threadIdx.x;
  __shared__ float As[32*256];
  {
    int l = tid >> 3, c8 = tid & 7;
    int tk = questions[b*QL_ + l];
    const float4* src = (const float4*)(emb + (size_t)tk*256) + c8*8;
    float4* dst = (float4*)(As + l*256 + c8*32);
    #pragma unroll
    for (int q = 0; q < 8; ++q) dst[q] = src[q];
  }
  __syncthreads();
  int rr = tid >> 7, jj = tid & 127;
  int n = n0 + jj;
  const float4* W4 = (const float4*)(Wx + ((size_t)dir*768 + n)*256);
  const float4* A4 = (const float4*)As;
  float acc[16];
  #pragma unroll
  for (int i = 0; i < 16; ++i) acc[i] = 0.f;
  for (int k4 = 0; k4 < 64; ++k4) {
    float4 wv = W4[k4];
    #pragma unroll
    for (int i = 0; i < 16; ++i) {
      float4 av = A4[(rr*16 + i)*64 + k4];
      acc[i] += av.x*wv.x + av.y*wv.y + av.z*wv.z + av.w*wv.w;
    }
  }
  float bias = bx[dir*768 + n];
  for (int i = 0; i < 16; ++i) {
    int l = rr*16 + i;
    xp[(((size_t)dir*QL_ + l)*16 + b)*768 + n] = acc[i] + bias;
  }
}

// ---------------------------------------------------------------------------
// Fused persistent GRU kernel, grid 252 x 512 -> ONE CU round.
// Desc blocks: M=128, 8 waves (2/SIMD -> 256 reg/wave budget). Each wave owns
// j-slices {jl, jl+128}. 3 MFMA phases (no barriers between; all read-only
// on A2): A: R(k=512)+G(k=256, a-frag shared kfx>=8) -> r, tp=r*(G+bg);
// B1: N(x) -> tp=tanh(N+bn+tp); B2: Z(k=512). Then 1 barrier + epilogue.
// h kept packed-fp16 in regs (recurrence numerics identical to LDS-fp16).
// Next-step gathers issued before epilogue (latency hidden under ~2.5k VALU).
// ---------------------------------------------------------------------------
__global__ __launch_bounds__(512, 2) void k_fused(
    const int* __restrict__ desc, const _Float16* __restrict__ emb16,
    const _Float16* __restrict__ Bd, const float* __restrict__ dbx,
    const float* __restrict__ dbh, float* __restrict__ dh,
    const int* __restrict__ questions, const _Float16* __restrict__ WhQ,
    const float* __restrict__ qbh, const float* __restrict__ xp,
    float* __restrict__ qwh, float* __restrict__ qemb)
{
  __shared__ __align__(16) char smem[137216];   // A2 128KB + tokens 6KB
  const int bid = blockIdx.x;
  const int tid = threadIdx.x;
  const int lane = tid & 63, w = tid >> 6;      // 8 waves
  const int lm = lane & 15, lq = lane >> 4;
  const int jl = w*16 + lm;                     // 0..127
  const int jl2 = jl + 128;

  if (bid < NBLK_DESC) {
    // ======================= desc-GRU path =======================
    const int dir  = (bid >= 125) ? 1 : 0;
    const int seq0 = (bid - dir*125) * MDESC;
    _Float16* A2   = (_Float16*)smem;                 // [128][512] swizzled
    int*      tokA = (int*)(smem + MDESC*512*2);      // 1536 tokens

    for (int i = tid; i < MDESC*DL_; i += 512)
      tokA[i] = desc[(size_t)seq0*DL_ + i];

    // zero h region (chunks 32..63 per row): 128 rows x 32 chunks, 8/thread
    {
      int row = tid >> 2, cc = tid & 3;
      half8 z8 = {0,0,0,0,0,0,0,0};
      #pragma unroll
      for (int q = 0; q < 8; ++q) {
        int c = 32 + cc*8 + q;
        *(half8*)(A2 + row*512 + ((c ^ (row & 63))*8)) = z8;
      }
    }
    __syncthreads();   // tokens visible for ldx

    const _Float16* Bdir = Bd + (size_t)dir * 393216;
    const _Float16* pR1 = Bdir + (size_t)jl *512;
    const _Float16* pR2 = Bdir + (size_t)jl2*512;
    const _Float16* pZ1 = Bdir + (size_t)(256 + jl )*512;
    const _Float16* pZ2 = Bdir + (size_t)(256 + jl2)*512;
    const _Float16* pX1 = Bdir + 262144 + (size_t)jl *256;
    const _Float16* pX2 = Bdir + 262144 + (size_t)jl2*256;
    const _Float16* pG1 = Bdir + 327680 + (size_t)jl *256;
    const _Float16* pG2 = Bdir + 327680 + (size_t)jl2*256;

    const float bias_r1 = dbx[dir*768 + jl ]       + dbh[dir*768 + jl ];
    const float bias_r2 = dbx[dir*768 + jl2]       + dbh[dir*768 + jl2];
    const float bias_z1 = dbx[dir*768 + 256 + jl ] + dbh[dir*768 + 256 + jl ];
    const float bias_z2 = dbx[dir*768 + 256 + jl2] + dbh[dir*768 + 256 + jl2];
    const float bias_n1 = dbx[dir*768 + 512 + jl ];
    const float bias_n2 = dbx[dir*768 + 512 + jl2];
    const float bias_g1 = dbh[dir*768 + 512 + jl ];
    const float bias_g2 = dbh[dir*768 + 512 + jl2];

    const int l0 = dir ? (DL_-1) : 0;
    const int dl = dir ? -1 : 1;

    // x staging: 4 threads/row, 128 B each (8 half8), NON-TEMPORAL gathers
    const int srow = tid >> 2, sp = tid & 3;
    half8 P[8];
    auto ldx = [&](int ll) {
      int tk = tokA[srow*DL_ + ll];
      const half8* src = (const half8*)(emb16 + (size_t)tk*256) + sp*8;
      #pragma unroll
      for (int q = 0; q < 8; ++q) P[q] = __builtin_nontemporal_load(src + q);
    };
    auto stw = [&]() {
      #pragma unroll
      for (int q = 0; q < 8; ++q) {
        int c = sp*8 + q;                             // x region chunks 0..31
        *(half8*)(A2 + srow*512 + ((c ^ (srow & 63))*8)) = P[q];
      }
    };
    ldx(l0); stw();                                   // stage x(step 0)
    __syncthreads();

    unsigned h2[8][4];                                // packed fp16 h: [mi][reg]
    #pragma unroll
    for (int mi = 0; mi < 8; ++mi)
      #pragma unroll
      for (int reg = 0; reg < 4; ++reg) h2[mi][reg] = 0u;

    int l = l0;
    for (int t = 0; t < DL_; ++t, l += dl) {
      // ---------- Phase A: R (k=512) + G (k=256 h-half, shared a-frags) ----
      floatx4 accR[8][2], accG[8][2];
      {
        floatx4 z4 = {0.f,0.f,0.f,0.f};
        #pragma unroll
        for (int mi = 0; mi < 8; ++mi) {
          accR[mi][0]=z4; accR[mi][1]=z4; accG[mi][0]=z4; accG[mi][1]=z4;
        }
      }
      #pragma unroll
      for (int kfx = 0; kfx < 16; ++kfx) {
        int k0 = kfx*32 + lq*8;
        half8 br1 = *(const half8*)(pR1 + k0);
        half8 br2 = *(const half8*)(pR2 + k0);
        half8 bg1, bg2;
        if (kfx >= 8) {
          int kg = (kfx-8)*32 + lq*8;
          bg1 = *(const half8*)(pG1 + kg);
          bg2 = *(const half8*)(pG2 + kg);
        }
        int cb = kfx*4 + lq;
        #pragma unroll
        for (int mi = 0; mi < 8; ++mi) {
          int row = mi*16 + lm;
          half8 a = *(const half8*)(A2 + row*512 + ((cb ^ (row & 63))*8));
          accR[mi][0] = __builtin_amdgcn_mfma_f32_16x16x32_f16(a, br1, accR[mi][0], 0,0,0);
          accR[mi][1] = __builtin_amdgcn_mfma_f32_16x16x32_f16(a, br2, accR[mi][1], 0,0,0);
          if (kfx >= 8) {
            accG[mi][0] = __builtin_amdgcn_mfma_f32_16x16x32_f16(a, bg1, accG[mi][0], 0,0,0);
            accG[mi][1] = __builtin_amdgcn_mfma_f32_16x16x32_f16(a, bg2, accG[mi][1], 0,0,0);
          }
        }
      }
      // A-epilog: tp = r * (G + bias_g)   (pure regs, no barrier)
      floatx4 tp[8][2];
      #pragma unroll
      for (int mi = 0; mi < 8; ++mi)
        #pragma unroll
        for (int nt = 0; nt < 2; ++nt)
          #pragma unroll
          for (int e = 0; e < 4; ++e) {
            float r = sigf(accR[mi][nt][e] + (nt ? bias_r2 : bias_r1));
            tp[mi][nt][e] = r * (accG[mi][nt][e] + (nt ? bias_g2 : bias_g1));
          }

      // ---------- Phase B1: N (x-half, k=256) ----------
      floatx4 accN[8][2];
      {
        floatx4 z4 = {0.f,0.f,0.f,0.f};
        #pragma unroll
        for (int mi = 0; mi < 8; ++mi) { accN[mi][0]=z4; accN[mi][1]=z4; }
      }
      #pragma unroll
      for (int kfx = 0; kfx < 8; ++kfx) {
        int k0 = kfx*32 + lq*8;
        half8 bx1 = *(const half8*)(pX1 + k0);
        half8 bx2 = *(const half8*)(pX2 + k0);
        int cb = kfx*4 + lq;                          // x chunks 0..31
        #pragma unroll
        for (int mi = 0; mi < 8; ++mi) {
          int row = mi*16 + lm;
          half8 a = *(const half8*)(A2 + row*512 + ((cb ^ (row & 63))*8));
          accN[mi][0] = __builtin_amdgcn_mfma_f32_16x16x32_f16(a, bx1, accN[mi][0], 0,0,0);
          accN[mi][1] = __builtin_amdgcn_mfma_f32_16x16x32_f16(a, bx2, accN[mi][1], 0,0,0);
        }
      }
      // B1-epilog: tp = tanh(N + bias_n + tp) = n_t
      #pragma unroll
      for (int mi = 0; mi < 8; ++mi)
        #pragma unroll
        for (int nt = 0; nt < 2; ++nt)
          #pragma unroll
          for (int e = 0; e < 4; ++e)
            tp[mi][nt][e] = tanhfast(accN[mi][nt][e] + (nt ? bias_n2 : bias_n1) + tp[mi][nt][e]);

      // ---------- Phase B2: Z (k=512) ----------
      floatx4 accZ[8][2];
      {
        floatx4 z4 = {0.f,0.f,0.f,0.f};
        #pragma unroll
        for (int mi = 0; mi < 8; ++mi) { accZ[mi][0]=z4; accZ[mi][1]=z4; }
      }
      #pragma unroll
      for (int kfx = 0; kfx < 16; ++kfx) {
        int k0 = kfx*32 + lq*8;
        half8 bz1 = *(const half8*)(pZ1 + k0);
        half8 bz2 = *(const half8*)(pZ2 + k0);
        int cb = kfx*4 + lq;
        #pragma unroll
        for (int mi = 0; mi < 8; ++mi) {
          int row = mi*16 + lm;
          half8 a = *(const half8*)(A2 + row*512 + ((cb ^ (row & 63))*8));
          accZ[mi][0] = __builtin_amdgcn_mfma_f32_16x16x32_f16(a, bz1, accZ[mi][0], 0,0,0);
          accZ[mi][1] = __builtin_amdgcn_mfma_f32_16x16x32_f16(a, bz2, accZ[mi][1], 0,0,0);
        }
      }

      __syncthreads();   // all A2 reads of step t done

      if (t < DL_-1) ldx(l + dl);   // issue next-step gathers; hide under epilogue

      #pragma unroll
      for (int mi = 0; mi < 8; ++mi) {
        #pragma unroll
        for (int reg = 0; reg < 4; ++reg) {
          int m = mi*16 + lq*4 + reg;
          int tk = tokA[m*DL_ + l];
          unsigned hp = h2[mi][reg];
          unsigned hpn = 0u;
          #pragma unroll
          for (int nt = 0; nt < 2; ++nt) {
            int j = nt ? jl2 : jl;
            unsigned short ub = nt ? (unsigned short)(hp >> 16)
                                   : (unsigned short)(hp & 0xFFFFu);
            float hold = (float)__builtin_bit_cast(_Float16, ub);
            float z  = sigf(accZ[mi][nt][reg] + (nt ? bias_z2 : bias_z1));
            float nv = tp[mi][nt][reg];
            float hn = (1.f - z)*nv + z*hold;
            float hnew = (tk != 0) ? hn : hold;
            _Float16 h16 = (_Float16)hnew;
            int c2 = 32 + (j >> 3);
            A2[m*512 + ((c2 ^ (m & 63))*8) + (j & 7)] = h16;
            if (t == DL_-1)
              dh[((size_t)dir*NSEQD + seq0 + m)*256 + j] = hnew;
            unsigned short nb = __builtin_bit_cast(unsigned short, h16);
            hpn |= nt ? ((unsigned)nb << 16) : (unsigned)nb;
          }
          h2[mi][reg] = hpn;
        }
      }
      if (t < DL_-1) stw();         // commit x(t+1)
      __syncthreads();              // h + x writes visible for next step
    }
  } else {
    // ======================= q-GRU path (8 waves, 2 j-slices/wave) ========
    const int dir = bid - NBLK_DESC;
    _Float16* hA   = (_Float16*)smem;                 // 16x256 swizzled (8 KB)
    int*      tokS = (int*)(smem + 8192);             // 512 ints

    tokS[tid] = questions[tid];
    {
      int row = tid >> 5, c = tid & 31;
      half8 z8 = {0,0,0,0,0,0,0,0};
      *(half8*)(hA + row*256 + ((c ^ row)*8)) = z8;
    }
    __syncthreads();

    const _Float16* pR1 = WhQ + ((size_t)dir*768 + jl )*256;
    const _Float16* pR2 = WhQ + ((size_t)dir*768 + jl2)*256;
    const _Float16* pZ1 = WhQ + ((size_t)dir*768 + 256 + jl )*256;
    const _Float16* pZ2 = WhQ + ((size_t)dir*768 + 256 + jl2)*256;
    const _Float16* pG1 = WhQ + ((size_t)dir*768 + 512 + jl )*256;
    const _Float16* pG2 = WhQ + ((size_t)dir*768 + 512 + jl2)*256;
    const float bh_r1 = qbh[dir*768 + jl ],       bh_r2 = qbh[dir*768 + jl2];
    const float bh_z1 = qbh[dir*768 + 256 + jl ], bh_z2 = qbh[dir*768 + 256 + jl2];
    const float bh_n1 = qbh[dir*768 + 512 + jl ], bh_n2 = qbh[dir*768 + 512 + jl2];

    float hreg[2][4];
    #pragma unroll
    for (int nt = 0; nt < 2; ++nt)
      #pragma unroll
      for (int reg = 0; reg < 4; ++reg) hreg[nt][reg] = 0.f;

    for (int t = 0; t < QL_; ++t) {
      int l = dir ? (QL_-1-t) : t;

      // x loads early (L2-hot xp), hidden under MFMA phase
      float xr[2][4], xz[2][4], xn[2][4];
      #pragma unroll
      for (int nt = 0; nt < 2; ++nt)
        #pragma unroll
        for (int reg = 0; reg < 4; ++reg) {
          int b = lq*4 + reg;
          int j = nt ? jl2 : jl;
          const float* xb = xp + (((size_t)dir*QL_ + l)*16 + b)*768;
          xr[nt][reg] = xb[j];
          xz[nt][reg] = xb[256 + j];
          xn[nt][reg] = xb[512 + j];
        }

      floatx4 aR[2], aZ[2], aG[2];
      {
        floatx4 z4 = {0.f,0.f,0.f,0.f};
        aR[0]=z4; aR[1]=z4; aZ[0]=z4; aZ[1]=z4; aG[0]=z4; aG[1]=z4;
      }
      #pragma unroll
      for (int kf = 0; kf < 8; ++kf) {
        int p = (kf*4 + lq) ^ lm;
        half8 a = *(const half8*)(hA + lm*256 + p*8);
        int k0 = kf*32 + lq*8;
        half8 br1 = *(const half8*)(pR1 + k0);
        half8 br2 = *(const half8*)(pR2 + k0);
        half8 bz1 = *(const half8*)(pZ1 + k0);
        half8 bz2 = *(const half8*)(pZ2 + k0);
        half8 bg1 = *(const half8*)(pG1 + k0);
        half8 bg2 = *(const half8*)(pG2 + k0);
        aR[0] = __builtin_amdgcn_mfma_f32_16x16x32_f16(a, br1, aR[0], 0,0,0);
        aR[1] = __builtin_amdgcn_mfma_f32_16x16x32_f16(a, br2, aR[1], 0,0,0);
        aZ[0] = __builtin_amdgcn_mfma_f32_16x16x32_f16(a, bz1, aZ[0], 0,0,0);
        aZ[1] = __builtin_amdgcn_mfma_f32_16x16x32_f16(a, bz2, aZ[1], 0,0,0);
        aG[0] = __builtin_amdgcn_mfma_f32_16x16x32_f16(a, bg1, aG[0], 0,0,0);
        aG[1] = __builtin_amdgcn_mfma_f32_16x16x32_f16(a, bg2, aG[1], 0,0,0);
      }
      __syncthreads();   // hA reads done before epilogue rewrites h

      #pragma unroll
      for (int nt = 0; nt < 2; ++nt)
        #pragma unroll
        for (int reg = 0; reg < 4; ++reg) {
          int b = lq*4 + reg;
          int j = nt ? jl2 : jl;
          float r  = sigf(xr[nt][reg] + aR[nt][reg] + (nt ? bh_r2 : bh_r1));
          float z  = sigf(xz[nt][reg] + aZ[nt][reg] + (nt ? bh_z2 : bh_z1));
          float nv = tanhfast(xn[nt][reg] + r*(aG[nt][reg] + (nt ? bh_n2 : bh_n1)));
          float hold = hreg[nt][reg];
          float hn = (1.f - z)*nv + z*hold;
          int tk = tokS[b*QL_ + l];
          float hnew = (tk != 0) ? hn : hold;
          hreg[nt][reg] = hnew;
          int p2 = (j >> 3) ^ b;
          hA[b*256 + p2*8 + (j & 7)] = (_Float16)hnew;
          qwh[((size_t)b*QL_ + l)*512 + dir*256 + j] = (tk != 0) ? hnew : 0.f;
        }
      __syncthreads();   // h writes visible for next MFMA
    }
    #pragma unroll
    for (int nt = 0; nt < 2; ++nt)
      #pragma unroll
      for (int reg = 0; reg < 4; ++reg) {
        int b = lq*4 + reg;
        int j = nt ? jl2 : jl;
        qemb[b*512 + dir*256 + j] = hreg[nt][reg];
      }
  }
}

// Per t: cq = tanh(q_emb @ step_W^T + b); att softmax; ctx; u = ctx*rel_W.
__global__ __launch_bounds__(256) void k_attn(
    const float* __restrict__ qemb, const float* __restrict__ qwh,
    const float* __restrict__ sW, const float* __restrict__ sb,
    const float* __restrict__ relW, float* __restrict__ u, int t)
{
  int b = blockIdx.x, tid = threadIdx.x;
  __shared__ float qe[512];
  __shared__ float cq[512];
  __shared__ float lg[32];
  __shared__ float dist[32];
  qe[tid]     = qemb[b*512 + tid];
  qe[tid+256] = qemb[b*512 + 256 + tid];
  __syncthreads();
  const float4* qe4 = (const float4*)qe;
  for (int nn = 0; nn < 2; ++nn) {
    int n = tid + nn*256;
    const float4* w4 = (const float4*)(sW + ((size_t)t*512 + n)*512);
    float acc = 0.f;
    for (int k4 = 0; k4 < 128; ++k4) {
      float4 w = w4[k4]; float4 q = qe4[k4];
      acc += w.x*q.x + w.y*q.y + w.z*q.z + w.w*q.w;
    }
    cq[n] = tanhfast(acc + sb[t*512 + n]);
  }
  __syncthreads();
  if (tid < 32) {
    const float4* r4 = (const float4*)(qwh + ((size_t)b*QL_ + tid)*512);
    const float4* c4 = (const float4*)cq;
    float acc = 0.f;
    for (int k4 = 0; k4 < 128; ++k4) {
      float4 w = r4[k4]; float4 q = c4[k4];
      acc += w.x*q.x + w.y*q.y + w.z*q.z + w.w*q.w;
    }
    lg[tid] = acc;
  }
  __syncthreads();
  if (tid == 0) {
    float mx = lg[0];
    for (int i = 1; i < 32; ++i) mx = fmaxf(mx, lg[i]);
    float s = 0.f;
    for (int i = 0; i < 32; ++i) { float e = __expf(lg[i]-mx); dist[i] = e; s += e; }
    float inv = __builtin_amdgcn_rcpf(s);
    for (int i = 0; i < 32; ++i) dist[i] *= inv;
  }
  __syncthreads();
  for (int nn = 0; nn < 2; ++nn) {
    int c = tid + nn*256;
    float acc = 0.f;
    #pragma unroll 4
    for (int ll = 0; ll < 32; ++ll)
      acc += dist[ll] * qwh[((size_t)b*QL_ + ll)*512 + c];
    u[b*512 + c] = acc * relW[c];
  }
}

__global__ __launch_bounds__(256) void k_dlogit(
    const float* __restrict__ u, const float* __restrict__ dh,
    const float* __restrict__ relb, float* __restrict__ dprob, int t)
{
  int w = threadIdx.x >> 6, lane = threadIdx.x & 63;
  int o = blockIdx.x*4 + w;
  int b = o / 500;
  int s = t*(B_*RSZ_) + o;
  const float* e0 = dh + (size_t)s*256;
  const float* e1 = dh + (size_t)NSEQD*256 + (size_t)s*256;
  float acc = 0.f;
  #pragma unroll
  for (int i = 0; i < 4; ++i) {
    int c = lane + i*64;
    acc += u[b*512 + c]       * e0[c];
    acc += u[b*512 + 256 + c] * e1[c];
  }
  #pragma unroll
  for (int off = 32; off; off >>= 1) acc += __shfl_down(acc, off);
  if (lane == 0) dprob[o] = sigf(acc + relb[0]);
}

__global__ void k_scatter(const int* __restrict__ pair, const float* __restrict__ dprob,
                          const float* __restrict__ esrc, float* __restrict__ edst,
                          int t, int clampflag)
{
  int o = blockIdx.x*256 + threadIdx.x;
  if (o >= B_*RSZ_) return;
  int b = o / RSZ_, r = o % RSZ_;
  const int* pp = pair + (((size_t)t*B_ + b)*RSZ_ + r)*2;
  int sub = pp[0], obj = pp[1];
  float v = esrc[(size_t)b*NE_ + sub];
  if (clampflag) v = fminf(v, 1.0f);
  atomicAdd(edst + (size_t)b*NE_ + obj, v * dprob[o]);
}

__global__ __launch_bounds__(256) void k_final(
    const float* __restrict__ qemb, const float* __restrict__ W,
    const float* __restrict__ bias, const float* __restrict__ efin,
    float* __restrict__ out)
{
  int tid = threadIdx.x;
  int lane = tid & 63;
  int ks = lane & 15, bg = lane >> 4;
  int b = (tid >> 6)*4 + bg;
  float q[32];
  {
    const float4* q4 = (const float4*)(qemb + b*512 + ks*32);
    #pragma unroll
    for (int i = 0; i < 8; ++i) {
      float4 v = q4[i];
      q[4*i]=v.x; q[4*i+1]=v.y; q[4*i+2]=v.z; q[4*i+3]=v.w;
    }
  }
  int e0 = blockIdx.x*256;
  int eend = (e0+256 < NE_) ? e0+256 : NE_;
  for (int e = e0; e < eend; e += 2) {        // 2 rows in flight for MLP
    const float4* w4a = (const float4*)(W + (size_t)e*512 + ks*32);
    const float4* w4b = (const float4*)(W + (size_t)(e+1)*512 + ks*32);
    float acca = 0.f, accb = 0.f;
    #pragma unroll
    for (int i = 0; i < 8; ++i) {
      float4 va = w4a[i];
      float4 vb = w4b[i];
      acca += va.x*q[4*i] + va.y*q[4*i+1] + va.z*q[4*i+2] + va.w*q[4*i+3];
      accb += vb.x*q[4*i] + vb.y*q[4*i+1] + vb.z*q[4*i+2] + vb.w*q[4*i+3];
    }
    acca += __shfl_xor(acca, 1); accb += __shfl_xor(accb, 1);
    acca += __shfl_xor(acca, 2); accb += __shfl_xor(accb, 2);
    acca += __shfl_xor(acca, 4); accb += __shfl_xor(accb, 4);
    acca += __shfl_xor(acca, 8); accb += __shfl_xor(accb, 8);
    if (ks == 0) {
      float mska = sigf(acca + bias[e]);
      float eva  = fminf(efin[(size_t)b*NE_ + e], 1.0f);
      out[(size_t)b*NE_ + e] = eva * mska;
      float mskb = sigf(accb + bias[e+1]);
      float evb  = fminf(efin[(size_t)b*NE_ + e+1], 1.0f);
      out[(size_t)b*NE_ + e+1] = evb * mskb;
    }
  }
}

extern "C" void kernel_launch(void* const* d_in, const int* in_sizes, int n_in,
                              void* d_out, int out_size, void* d_ws, size_t ws_size,
                              hipStream_t stream)
{
  const int*   questions = (const int*)d_in[0];
  const float* e_s   = (const float*)d_in[1];
  const int*   pair  = (const int*)d_in[2];
  const int*   desc  = (const int*)d_in[3];
  const float* emb   = (const float*)d_in[4];
  const float* qWx   = (const float*)d_in[5];
  const float* qWh   = (const float*)d_in[6];
  const float* qbx   = (const float*)d_in[7];
  const float* qbh   = (const float*)d_in[8];
  const float* dWx   = (const float*)d_in[9];
  const float* dWh   = (const float*)d_in[10];
  const float* dbx   = (const float*)d_in[11];
  const float* dbh   = (const float*)d_in[12];
  const float* stepW = (const float*)d_in[13];
  const float* stepb = (const float*)d_in[14];
  const float* relW  = (const float*)d_in[15];
  const float* relb  = (const float*)d_in[16];
  const float* qclsW = (const float*)d_in[17];
  const float* qclsb = (const float*)d_in[18];
  float* out = (float*)d_out;

  char* ws = (char*)d_ws;
  size_t off = 0;
  auto alloc = [&](size_t bytes)->void* {
    void* p = ws + off; off += (bytes + 255) & ~(size_t)255; return p;
  };
  _Float16* Bd   = (_Float16*)alloc((size_t)2*393216*sizeof(_Float16)); // 1.5 MB
  _Float16* WhQ  = (_Float16*)alloc((size_t)2*768*256*sizeof(_Float16));// 0.75 MB
  _Float16* emb16= (_Float16*)alloc((size_t)NW_*256*sizeof(_Float16));  // 25.6 MB
  float* xp   = (float*)alloc((size_t)2*QL_*16*768*sizeof(float));      // 3.1 MB
  float* qemb = (float*)alloc((size_t)16*512*sizeof(float));
  float* qwh  = (float*)alloc((size_t)16*QL_*512*sizeof(float));        // 1 MB
  float* dh   = (float*)alloc((size_t)2*NSEQD*256*sizeof(float));       // 32.8 MB
  float* u    = (float*)alloc((size_t)16*512*sizeof(float));
  float* dprob= (float*)alloc((size_t)B_*RSZ_*sizeof(float));
  // ebuf aliases emb16 (dead after k_fused); zeroed after k_fused completes.
  float* ebuf = (float*)emb16;                                          // 12.8 MB

  k_prep_desc<<<3072, 256, 0, stream>>>(dWx, dWh, Bd);
  k_prep_qwh<<<1536, 256, 0, stream>>>(qWh, WhQ);
  k_prep_emb16<<<6250, 256, 0, stream>>>(emb, emb16);

  k_xproj<<<dim3(16,6,2), 256, 0, stream>>>(questions, emb, qWx, qbx, xp);

  k_fused<<<NBLK_FUSED, 512, 0, stream>>>(desc, emb16, Bd, dbx, dbh, dh,
                                          questions, WhQ, qbh, xp, qwh, qemb);

  hipMemsetAsync(ebuf, 0, (size_t)2*B_*NE_*sizeof(float), stream);

  for (int t = 0; t < T_; ++t) {
    k_attn<<<16, 256, 0, stream>>>(qemb, qwh, stepW, stepb, relW, u, t);
    k_dlogit<<<2000, 256, 0, stream>>>(u, dh, relb, dprob, t);
    const float* esrc = (t == 0) ? e_s : ebuf;
    float* edst = ebuf + (size_t)t*B_*NE_;
    k_scatter<<<32, 256, 0, stream>>>(pair, dprob, esrc, edst, t, t);
  }
  k_final<<<(NE_+255)/256, 256, 0, stream>>>(qemb, qclsW, qclsb, ebuf + (size_t)B_*NE_, out);
}